// Round 1
// baseline (332.209 us; speedup 1.0000x reference)
//
#include <hip/hip_runtime.h>
#include <math.h>

#define BATCH   16
#define CH      512           // sequence length L == channels
#define HW      4096          // 64*64
#define NCHUNK  64
#define ROWS    (HW / NCHUNK) // 64 rows per chunk
#define DSTATE  16

__device__ __forceinline__ float siluf(float x) {
    return x / (1.0f + expf(-x));
}
__device__ __forceinline__ float softplusf(float x) {
    return (x > 20.0f) ? x : log1pf(expf(x));
}

// ---------------- K1a: GAP partial sums (deterministic, coalesced) ----------
__global__ void gap_partial(const float* __restrict__ x1, float* __restrict__ partial) {
    int b     = blockIdx.x / NCHUNK;
    int chunk = blockIdx.x % NCHUNK;
    int c     = threadIdx.x;                       // 0..511
    const float* p = x1 + ((size_t)b * HW + (size_t)chunk * ROWS) * CH + c;
    float s = 0.f;
    #pragma unroll 4
    for (int r = 0; r < ROWS; ++r) s += p[(size_t)r * CH];
    partial[(chunk * BATCH + b) * CH + c] = s;
}

// ---------------- K1b: GAP finalize ----------------------------------------
__global__ void gap_final(const float* __restrict__ partial, float* __restrict__ pooled) {
    int i = blockIdx.x * blockDim.x + threadIdx.x; // i = b*CH + c, 0..8191
    float s = 0.f;
    #pragma unroll 8
    for (int k = 0; k < NCHUNK; ++k) s += partial[k * (BATCH * CH) + i];
    pooled[i] = s * (1.0f / (float)HW);
}

// ---------------- K2a: per-position Mamba precompute ------------------------
// Everything except the sequential scan: conv+silu, projections, softplus,
// dA = exp(dt*A), dBu = dt*B*x, C, gate coef = silu(z)*out_w, skip term.
__global__ void mamba_pre(const float* __restrict__ pooled,
                          const float* __restrict__ in_proj_w,   // [4]
                          const float* __restrict__ conv_w,      // [2][4]
                          const float* __restrict__ conv_b,      // [2]
                          const float* __restrict__ x_proj_w,    // [33][2]
                          const float* __restrict__ dt_proj_w,   // [2]
                          const float* __restrict__ dt_proj_b,   // [2]
                          const float* __restrict__ A_log,       // [2][16]
                          const float* __restrict__ Dp,          // [2]
                          const float* __restrict__ out_proj_w,  // [2]
                          float* __restrict__ dA,                // [B][L][2][16]
                          float* __restrict__ dBu,               // [B][L][2][16]
                          float* __restrict__ Cm,                // [B][L][16]
                          float* __restrict__ coef,              // [B][L][2]
                          float* __restrict__ skip)              // [B][L]
{
    int i = blockIdx.x * blockDim.x + threadIdx.x;  // b*CH + l
    if (i >= BATCH * CH) return;
    int b = i >> 9, l = i & (CH - 1);
    const float* pb = pooled + b * CH;
    float u0  = pb[l];
    float um1 = (l >= 1) ? pb[l - 1] : 0.f;
    float um2 = (l >= 2) ? pb[l - 2] : 0.f;
    float um3 = (l >= 3) ? pb[l - 3] : 0.f;

    float xs[2], g[2], dtv[2];
    #pragma unroll
    for (int d = 0; d < 2; ++d) {
        // x (pre-conv) = u * in_proj_w[d]; causal corr with conv_w[d][0..3]
        float conv = um3 * conv_w[d * 4 + 0] + um2 * conv_w[d * 4 + 1] +
                     um1 * conv_w[d * 4 + 2] + u0  * conv_w[d * 4 + 3];
        float xc = in_proj_w[d] * conv + conv_b[d];
        xs[d] = siluf(xc);
        float z = u0 * in_proj_w[2 + d];
        g[d] = siluf(z);
    }
    float dt_raw = xs[0] * x_proj_w[0] + xs[1] * x_proj_w[1];
    #pragma unroll
    for (int d = 0; d < 2; ++d)
        dtv[d] = softplusf(dt_raw * dt_proj_w[d] + dt_proj_b[d]);

    float sk = 0.f;
    #pragma unroll
    for (int d = 0; d < 2; ++d) {
        float cf = g[d] * out_proj_w[d];
        coef[i * 2 + d] = cf;
        sk += xs[d] * Dp[d] * cf;
    }
    skip[i] = sk;

    #pragma unroll
    for (int s = 0; s < DSTATE; ++s) {
        float Bs = xs[0] * x_proj_w[(1 + s) * 2]  + xs[1] * x_proj_w[(1 + s) * 2 + 1];
        float Cs = xs[0] * x_proj_w[(17 + s) * 2] + xs[1] * x_proj_w[(17 + s) * 2 + 1];
        Cm[i * DSTATE + s] = Cs;
        #pragma unroll
        for (int d = 0; d < 2; ++d) {
            float Aval = -expf(A_log[d * DSTATE + s]);
            dA [i * 32 + d * DSTATE + s] = expf(dtv[d] * Aval);
            dBu[i * 32 + d * DSTATE + s] = dtv[d] * Bs * xs[d];
        }
    }
}

// ---------------- K2b: sequential scan, 2 batches per wave ------------------
__global__ void __launch_bounds__(64) mamba_scan(const float* __restrict__ dA,
                                                 const float* __restrict__ dBu,
                                                 const float* __restrict__ Cm,
                                                 const float* __restrict__ coef,
                                                 const float* __restrict__ skip,
                                                 float* __restrict__ att)
{
    int lane = threadIdx.x;                 // 0..63
    int b    = blockIdx.x * 2 + (lane >> 5);
    int l32  = lane & 31;                   // (d,s) slot
    int s    = lane & 15;
    int d    = (lane >> 4) & 1;
    const float* pA    = dA   + (size_t)b * CH * 32 + l32;
    const float* pB    = dBu  + (size_t)b * CH * 32 + l32;
    const float* pC    = Cm   + (size_t)b * CH * DSTATE + s;
    const float* pcoef = coef + (size_t)b * CH * 2 + d;
    const float* pskip = skip + (size_t)b * CH;
    float*       patt  = att  + (size_t)b * CH;

    float h = 0.f;
    #pragma unroll 4
    for (int l = 0; l < CH; ++l) {
        float a  = pA[l * 32];
        float bb = pB[l * 32];
        h = fmaf(a, h, bb);                 // the only dependent chain
        float p = h * pC[l * DSTATE];
        p += __shfl_xor(p, 1, 16);
        p += __shfl_xor(p, 2, 16);
        p += __shfl_xor(p, 4, 16);
        p += __shfl_xor(p, 8, 16);          // all 16 lanes of the s-group hold y_d
        float q = p * pcoef[l * 2];
        q += __shfl_xor(q, 16, 32);         // combine d=0 and d=1 within the 32-lane half
        if (l32 == 0) patt[l] = pskip[l] + q;
    }
}

// ---------------- K3: out = x2 * att broadcast ------------------------------
__global__ void apply_att(const float4* __restrict__ x2,
                          const float4* __restrict__ att4,
                          float4* __restrict__ out, int n4)
{
    int stride = gridDim.x * blockDim.x;
    for (int i = blockIdx.x * blockDim.x + threadIdx.x; i < n4; i += stride) {
        float4 v = x2[i];
        // 2^19 float4 per batch; 128 float4 per (h,w) row of channels
        float4 a = att4[((i >> 19) << 7) + (i & 127)];
        v.x *= a.x; v.y *= a.y; v.z *= a.z; v.w *= a.w;
        out[i] = v;
    }
}

extern "C" void kernel_launch(void* const* d_in, const int* in_sizes, int n_in,
                              void* d_out, int out_size, void* d_ws, size_t ws_size,
                              hipStream_t stream) {
    const float* x1         = (const float*)d_in[0];
    const float* x2         = (const float*)d_in[1];
    const float* in_proj_w  = (const float*)d_in[2];
    const float* conv_w     = (const float*)d_in[3];
    const float* conv_b     = (const float*)d_in[4];
    const float* x_proj_w   = (const float*)d_in[5];
    const float* dt_proj_w  = (const float*)d_in[6];
    const float* dt_proj_b  = (const float*)d_in[7];
    const float* A_log      = (const float*)d_in[8];
    const float* Dp         = (const float*)d_in[9];
    const float* out_proj_w = (const float*)d_in[10];

    float* ws = (float*)d_ws;
    // layout (floats). partial aliases the dA.. region's space safely:
    // pooled [0,8192); then dA(262144) dBu(262144) Cm(131072) coef(16384)
    // skip(8192) att(8192); partial(524288) placed after pooled and is dead
    // before dA is written, so dA region may overlap it — but keep simple:
    size_t o = 0;
    float* pooled  = ws + o; o += BATCH * CH;                 // 8192
    float* partial = ws + o;                                   // 524288 (scratch, dead after gap_final)
    float* dAv     = ws + o; o += 262144;                      // aliases partial (safe: written after)
    float* dBuv    = ws + o; o += 262144;
    float* Cmv     = ws + o; o += 131072;
    float* coefv   = ws + o; o += 16384;
    float* skipv   = ws + o; o += 8192;
    float* attv    = ws + o; o += 8192;
    (void)ws_size; (void)in_sizes; (void)n_in; (void)out_size;

    gap_partial<<<BATCH * NCHUNK, CH, 0, stream>>>(x1, partial);
    gap_final<<<BATCH, CH, 0, stream>>>(partial, pooled);
    mamba_pre<<<(BATCH * CH) / 256, 256, 0, stream>>>(pooled, in_proj_w, conv_w, conv_b,
                                                      x_proj_w, dt_proj_w, dt_proj_b,
                                                      A_log, Dp, out_proj_w,
                                                      dAv, dBuv, Cmv, coefv, skipv);
    mamba_scan<<<BATCH / 2, 64, 0, stream>>>(dAv, dBuv, Cmv, coefv, skipv, attv);

    int n4 = (BATCH * HW * CH) / 4;  // 8388608
    apply_att<<<4096, 256, 0, stream>>>((const float4*)x2, (const float4*)attv,
                                        (float4*)d_out, n4);
}

// Round 2
// 124.618 us; speedup vs baseline: 2.6658x; 2.6658x over previous
//
#include <hip/hip_runtime.h>
#include <math.h>

#define BATCH   16
#define CH      512           // sequence length L == channels
#define HW      4096          // 64*64
#define NCHUNK  64
#define ROWS    (HW / NCHUNK) // 64 rows per chunk
#define DSTATE  16
#define SCHUNK  16            // scan chunks per sequence
#define CLEN    (CH / SCHUNK) // 32 steps per chunk

__device__ __forceinline__ float siluf(float x) {
    return x / (1.0f + expf(-x));
}
__device__ __forceinline__ float softplusf(float x) {
    return (x > 20.0f) ? x : log1pf(expf(x));
}

// ---------------- K1a: GAP partial sums (deterministic, coalesced) ----------
__global__ void gap_partial(const float* __restrict__ x1, float* __restrict__ partial) {
    int b     = blockIdx.x / NCHUNK;
    int chunk = blockIdx.x % NCHUNK;
    int c     = threadIdx.x;                       // 0..511
    const float* p = x1 + ((size_t)b * HW + (size_t)chunk * ROWS) * CH + c;
    float s = 0.f;
    #pragma unroll 4
    for (int r = 0; r < ROWS; ++r) s += p[(size_t)r * CH];
    partial[(chunk * BATCH + b) * CH + c] = s;
}

// ---------------- K1b: GAP finalize ----------------------------------------
__global__ void gap_final(const float* __restrict__ partial, float* __restrict__ pooled) {
    int i = blockIdx.x * blockDim.x + threadIdx.x; // i = b*CH + c, 0..8191
    float s = 0.f;
    #pragma unroll 8
    for (int k = 0; k < NCHUNK; ++k) s += partial[k * (BATCH * CH) + i];
    pooled[i] = s * (1.0f / (float)HW);
}

// ---------------- K2a: per-position Mamba precompute ------------------------
// Everything except the sequential scan: conv+silu, projections, softplus,
// dA = exp(dt*A), dBu = dt*B*x, Cc = C * silu(z)*out_w (coef folded in),
// skip = sum_d x*Dp*coef.
__global__ void mamba_pre(const float* __restrict__ pooled,
                          const float* __restrict__ in_proj_w,   // [4]
                          const float* __restrict__ conv_w,      // [2][4]
                          const float* __restrict__ conv_b,      // [2]
                          const float* __restrict__ x_proj_w,    // [33][2]
                          const float* __restrict__ dt_proj_w,   // [2]
                          const float* __restrict__ dt_proj_b,   // [2]
                          const float* __restrict__ A_log,       // [2][16]
                          const float* __restrict__ Dp,          // [2]
                          const float* __restrict__ out_proj_w,  // [2]
                          float* __restrict__ dA,                // [B][L][2][16]
                          float* __restrict__ dBu,               // [B][L][2][16]
                          float* __restrict__ Cc,                // [B][L][2][16]
                          float* __restrict__ skip)              // [B][L]
{
    int i = blockIdx.x * blockDim.x + threadIdx.x;  // b*CH + l
    if (i >= BATCH * CH) return;
    int b = i >> 9, l = i & (CH - 1);
    const float* pb = pooled + b * CH;
    float u0  = pb[l];
    float um1 = (l >= 1) ? pb[l - 1] : 0.f;
    float um2 = (l >= 2) ? pb[l - 2] : 0.f;
    float um3 = (l >= 3) ? pb[l - 3] : 0.f;

    float xs[2], cf[2], dtv[2];
    #pragma unroll
    for (int d = 0; d < 2; ++d) {
        float conv = um3 * conv_w[d * 4 + 0] + um2 * conv_w[d * 4 + 1] +
                     um1 * conv_w[d * 4 + 2] + u0  * conv_w[d * 4 + 3];
        float xc = in_proj_w[d] * conv + conv_b[d];
        xs[d] = siluf(xc);
        float z = u0 * in_proj_w[2 + d];
        cf[d] = siluf(z) * out_proj_w[d];
    }
    float dt_raw = xs[0] * x_proj_w[0] + xs[1] * x_proj_w[1];
    #pragma unroll
    for (int d = 0; d < 2; ++d)
        dtv[d] = softplusf(dt_raw * dt_proj_w[d] + dt_proj_b[d]);

    skip[i] = xs[0] * Dp[0] * cf[0] + xs[1] * Dp[1] * cf[1];

    #pragma unroll
    for (int s = 0; s < DSTATE; ++s) {
        float Bs = xs[0] * x_proj_w[(1 + s) * 2]  + xs[1] * x_proj_w[(1 + s) * 2 + 1];
        float Cs = xs[0] * x_proj_w[(17 + s) * 2] + xs[1] * x_proj_w[(17 + s) * 2 + 1];
        #pragma unroll
        for (int d = 0; d < 2; ++d) {
            float Aval = -expf(A_log[d * DSTATE + s]);
            dA [i * 32 + d * DSTATE + s] = expf(dtv[d] * Aval);
            dBu[i * 32 + d * DSTATE + s] = dtv[d] * Bs * xs[d];
            Cc [i * 32 + d * DSTATE + s] = Cs * cf[d];
        }
    }
}

// ---------------- K2b: chunked parallel linear-recurrence scan --------------
// One block per batch. 512 threads = SCHUNK(16) chunks x 32 (d,s) lanes.
// Phase 1: per-chunk (P = prod dA, Q = local scan from 0).
// Phase 2: exclusive prefix compose across chunks via LDS (<=15 fmas).
// Phase 3: exact sequential recurrence within chunk from composed prefix;
//          y[l] = skip[l] + sum_{ds} h * Cc via 5x shfl_xor over 32 lanes.
__global__ void __launch_bounds__(512) mamba_scan2(const float* __restrict__ dA,
                                                   const float* __restrict__ dBu,
                                                   const float* __restrict__ Cc,
                                                   const float* __restrict__ skip,
                                                   float* __restrict__ att)
{
    int b     = blockIdx.x;
    int tid   = threadIdx.x;
    int ds    = tid & 31;
    int chunk = tid >> 5;
    size_t base = ((size_t)b * CH + (size_t)chunk * CLEN) * 32 + ds;
    const float* pA = dA  + base;
    const float* pB = dBu + base;
    const float* pC = Cc  + base;
    const float* psk = skip + (size_t)b * CH + chunk * CLEN;
    float*       patt = att + (size_t)b * CH + chunk * CLEN;

    // Phase 1
    float P = 1.f, Q = 0.f;
    #pragma unroll
    for (int l = 0; l < CLEN; ++l) {
        float a  = pA[l * 32];
        float bb = pB[l * 32];
        P *= a;
        Q = fmaf(a, Q, bb);
    }

    // Phase 2
    __shared__ float sP[SCHUNK][32];
    __shared__ float sQ[SCHUNK][32];
    sP[chunk][ds] = P;
    sQ[chunk][ds] = Q;
    __syncthreads();
    float h = 0.f;
    for (int j = 0; j < chunk; ++j)
        h = fmaf(sP[j][ds], h, sQ[j][ds]);

    // Phase 3
    #pragma unroll
    for (int l = 0; l < CLEN; ++l) {
        float a  = pA[l * 32];
        float bb = pB[l * 32];
        h = fmaf(a, h, bb);
        float p = h * pC[l * 32];
        p += __shfl_xor(p, 1, 32);
        p += __shfl_xor(p, 2, 32);
        p += __shfl_xor(p, 4, 32);
        p += __shfl_xor(p, 8, 32);
        p += __shfl_xor(p, 16, 32);
        if (ds == 0) patt[l] = psk[l] + p;
    }
}

// ---------------- K3: out = x2 * att broadcast ------------------------------
__global__ void apply_att(const float4* __restrict__ x2,
                          const float4* __restrict__ att4,
                          float4* __restrict__ out, int n4)
{
    int stride = gridDim.x * blockDim.x;
    for (int i = blockIdx.x * blockDim.x + threadIdx.x; i < n4; i += stride) {
        float4 v = x2[i];
        float4 a = att4[((i >> 19) << 7) + (i & 127)];
        v.x *= a.x; v.y *= a.y; v.z *= a.z; v.w *= a.w;
        out[i] = v;
    }
}

extern "C" void kernel_launch(void* const* d_in, const int* in_sizes, int n_in,
                              void* d_out, int out_size, void* d_ws, size_t ws_size,
                              hipStream_t stream) {
    const float* x1         = (const float*)d_in[0];
    const float* x2         = (const float*)d_in[1];
    const float* in_proj_w  = (const float*)d_in[2];
    const float* conv_w     = (const float*)d_in[3];
    const float* conv_b     = (const float*)d_in[4];
    const float* x_proj_w   = (const float*)d_in[5];
    const float* dt_proj_w  = (const float*)d_in[6];
    const float* dt_proj_b  = (const float*)d_in[7];
    const float* A_log      = (const float*)d_in[8];
    const float* Dp         = (const float*)d_in[9];
    const float* out_proj_w = (const float*)d_in[10];

    float* ws = (float*)d_ws;
    // partial (524288) aliases dA+dBu (262144+262144): partial is consumed by
    // gap_final before mamba_pre writes dA/dBu (same stream, ordered). Safe.
    size_t o = 0;
    float* pooled  = ws + o; o += BATCH * CH;                  // 8192
    float* partial = ws + o;                                   // scratch, dead after gap_final
    float* dAv     = ws + o; o += 262144;
    float* dBuv    = ws + o; o += 262144;
    float* Ccv     = ws + o; o += 262144;
    float* skipv   = ws + o; o += 8192;
    float* attv    = ws + o; o += 8192;
    (void)ws_size; (void)in_sizes; (void)n_in; (void)out_size;

    gap_partial<<<BATCH * NCHUNK, CH, 0, stream>>>(x1, partial);
    gap_final<<<BATCH, CH, 0, stream>>>(partial, pooled);
    mamba_pre<<<(BATCH * CH) / 256, 256, 0, stream>>>(pooled, in_proj_w, conv_w, conv_b,
                                                      x_proj_w, dt_proj_w, dt_proj_b,
                                                      A_log, Dp, out_proj_w,
                                                      dAv, dBuv, Ccv, skipv);
    mamba_scan2<<<BATCH, 512, 0, stream>>>(dAv, dBuv, Ccv, skipv, attv);

    int n4 = (BATCH * HW * CH) / 4;  // 8388608
    apply_att<<<4096, 256, 0, stream>>>((const float4*)x2, (const float4*)attv,
                                        (float4*)d_out, n4);
}

// Round 4
// 88.708 us; speedup vs baseline: 3.7450x; 1.4048x over previous
//
#include <hip/hip_runtime.h>
#include <math.h>

#define BATCH   16
#define CH      512           // sequence length L == channels
#define HW      4096          // 64*64
#define NCHUNK  64
#define ROWS    (HW / NCHUNK) // 64 rows per chunk
#define DSTATE  16
#define SCHUNK  16            // scan chunks per sequence
#define CLEN    (CH / SCHUNK) // 32 steps per chunk

typedef float f4 __attribute__((ext_vector_type(4)));

__device__ __forceinline__ float siluf(float x) {
    return x / (1.0f + expf(-x));
}
__device__ __forceinline__ float softplusf(float x) {
    return (x > 20.0f) ? x : log1pf(expf(x));
}

// ---------------- K1: GAP partial sums, float4 nontemporal ------------------
__global__ void __launch_bounds__(512) gap_partial(const f4* __restrict__ x1,
                                                   f4* __restrict__ partial) {
    int b     = blockIdx.x / NCHUNK;
    int chunk = blockIdx.x % NCHUNK;
    int t  = threadIdx.x;
    int c4 = t & 127;       // float4 column (128 per row of 512 ch)
    int rg = t >> 7;        // 4 row groups
    const f4* p = x1 + ((size_t)b * HW + (size_t)chunk * ROWS) * 128 + c4;
    f4 acc = (f4)(0.f);
    #pragma unroll
    for (int r = rg; r < ROWS; r += 4) {
        f4 v = __builtin_nontemporal_load(p + (size_t)r * 128);
        acc += v;
    }
    __shared__ f4 red[4][128];
    red[rg][c4] = acc;
    __syncthreads();
    if (rg == 0) {
        f4 s = red[0][c4] + red[1][c4] + red[2][c4] + red[3][c4];
        partial[(size_t)(chunk * BATCH + b) * 128 + c4] = s;
    }
}

// ---------------- K2: fused finalize + precompute + parallel scan -----------
// One block per batch, 512 threads. Everything between the two big streaming
// kernels stays in LDS/registers — no global round-trips, one launch.
__global__ void __launch_bounds__(512) mamba_fused(const float* __restrict__ partial,
                                                   const float* __restrict__ in_proj_w,
                                                   const float* __restrict__ conv_w,
                                                   const float* __restrict__ conv_b,
                                                   const float* __restrict__ x_proj_w,
                                                   const float* __restrict__ dt_proj_w,
                                                   const float* __restrict__ dt_proj_b,
                                                   const float* __restrict__ A_log,
                                                   const float* __restrict__ Dp,
                                                   const float* __restrict__ out_proj_w,
                                                   float* __restrict__ att)
{
    int b   = blockIdx.x;
    int tid = threadIdx.x;

    // --- 1) finalize pooled row ---
    __shared__ float pool[CH];
    {
        float s = 0.f;
        #pragma unroll 8
        for (int k = 0; k < NCHUNK; ++k)
            s += partial[(size_t)k * (BATCH * CH) + b * CH + tid];
        pool[tid] = s * (1.0f / (float)HW);
    }
    __syncthreads();

    // --- 2) per-position: conv+silu, gate coef, softplus(dt), skip ---
    __shared__ float sx0[CH], sx1[CH], sdt0[CH], sdt1[CH], scf0[CH], scf1[CH], ssk[CH];
    {
        int l = tid;
        float u0  = pool[l];
        float um1 = (l >= 1) ? pool[l - 1] : 0.f;
        float um2 = (l >= 2) ? pool[l - 2] : 0.f;
        float um3 = (l >= 3) ? pool[l - 3] : 0.f;
        float xs[2], cf[2], dtv[2];
        #pragma unroll
        for (int d = 0; d < 2; ++d) {
            float conv = um3 * conv_w[d * 4 + 0] + um2 * conv_w[d * 4 + 1] +
                         um1 * conv_w[d * 4 + 2] + u0  * conv_w[d * 4 + 3];
            float xc = in_proj_w[d] * conv + conv_b[d];
            xs[d] = siluf(xc);
            float z = u0 * in_proj_w[2 + d];
            cf[d] = siluf(z) * out_proj_w[d];
        }
        float dt_raw = xs[0] * x_proj_w[0] + xs[1] * x_proj_w[1];
        #pragma unroll
        for (int d = 0; d < 2; ++d)
            dtv[d] = softplusf(dt_raw * dt_proj_w[d] + dt_proj_b[d]);
        sx0[l] = xs[0]; sx1[l] = xs[1];
        sdt0[l] = dtv[0]; sdt1[l] = dtv[1];
        scf0[l] = cf[0]; scf1[l] = cf[1];
        ssk[l] = xs[0] * Dp[0] * cf[0] + xs[1] * Dp[1] * cf[1];
    }
    __syncthreads();

    // --- 3) chunked parallel scan: 16 chunks x 32 (d,s) lanes ---
    int ds    = tid & 31;
    int chunk = tid >> 5;
    int si    = ds & 15;
    int d     = ds >> 4;
    float Aval = -expf(A_log[d * DSTATE + si]);
    float wB0 = x_proj_w[(1 + si) * 2],  wB1 = x_proj_w[(1 + si) * 2 + 1];
    float wC0 = x_proj_w[(17 + si) * 2], wC1 = x_proj_w[(17 + si) * 2 + 1];
    const float* sdt = d ? sdt1 : sdt0;
    const float* scf = d ? scf1 : scf0;
    const float* sxd = d ? sx1  : sx0;

    float a_[CLEN], b_[CLEN], c_[CLEN];
    int l0 = chunk * CLEN;
    #pragma unroll
    for (int l = 0; l < CLEN; ++l) {
        int L = l0 + l;
        float x0 = sx0[L], x1v = sx1[L];
        float dt = sdt[L];
        float Bs = x0 * wB0 + x1v * wB1;
        float Cs = x0 * wC0 + x1v * wC1;
        a_[l] = expf(dt * Aval);
        b_[l] = dt * Bs * sxd[L];
        c_[l] = Cs * scf[L];
    }

    // phase 1: per-chunk (P, Q)
    float P = 1.f, Q = 0.f;
    #pragma unroll
    for (int l = 0; l < CLEN; ++l) { P *= a_[l]; Q = fmaf(a_[l], Q, b_[l]); }

    // phase 2: exclusive prefix compose across chunks
    __shared__ float sP[SCHUNK][32], sQ[SCHUNK][32];
    sP[chunk][ds] = P; sQ[chunk][ds] = Q;
    __syncthreads();
    float h = 0.f;
    for (int j = 0; j < chunk; ++j) h = fmaf(sP[j][ds], h, sQ[j][ds]);

    // phase 3: exact in-chunk recurrence + 32-lane reduce
    float* patt = att + (size_t)b * CH + l0;
    #pragma unroll
    for (int l = 0; l < CLEN; ++l) {
        h = fmaf(a_[l], h, b_[l]);
        float p = h * c_[l];
        p += __shfl_xor(p, 1, 32);
        p += __shfl_xor(p, 2, 32);
        p += __shfl_xor(p, 4, 32);
        p += __shfl_xor(p, 8, 32);
        p += __shfl_xor(p, 16, 32);
        if (ds == 0) patt[l] = ssk[l0 + l] + p;
    }
}

// ---------------- K3: out = x2 * att broadcast ------------------------------
__global__ void apply_att(const f4* __restrict__ x2,
                          const f4* __restrict__ att4,
                          f4* __restrict__ out, int n4)
{
    int stride = gridDim.x * blockDim.x;
    for (int i = blockIdx.x * blockDim.x + threadIdx.x; i < n4; i += stride) {
        f4 v = __builtin_nontemporal_load(x2 + i);
        f4 a = att4[((i >> 19) << 7) + (i & 127)];
        v *= a;
        __builtin_nontemporal_store(v, out + i);
    }
}

extern "C" void kernel_launch(void* const* d_in, const int* in_sizes, int n_in,
                              void* d_out, int out_size, void* d_ws, size_t ws_size,
                              hipStream_t stream) {
    const float* x1         = (const float*)d_in[0];
    const float* x2         = (const float*)d_in[1];
    const float* in_proj_w  = (const float*)d_in[2];
    const float* conv_w     = (const float*)d_in[3];
    const float* conv_b     = (const float*)d_in[4];
    const float* x_proj_w   = (const float*)d_in[5];
    const float* dt_proj_w  = (const float*)d_in[6];
    const float* dt_proj_b  = (const float*)d_in[7];
    const float* A_log      = (const float*)d_in[8];
    const float* Dp         = (const float*)d_in[9];
    const float* out_proj_w = (const float*)d_in[10];

    float* ws = (float*)d_ws;
    size_t o = 0;
    float* partial = ws + o; o += (size_t)NCHUNK * BATCH * CH;  // 524288
    float* attv    = ws + o; o += BATCH * CH;                   // 8192
    (void)ws_size; (void)in_sizes; (void)n_in; (void)out_size;

    gap_partial<<<BATCH * NCHUNK, 512, 0, stream>>>((const f4*)x1, (f4*)partial);
    mamba_fused<<<BATCH, 512, 0, stream>>>(partial, in_proj_w, conv_w, conv_b,
                                           x_proj_w, dt_proj_w, dt_proj_b,
                                           A_log, Dp, out_proj_w, attv);
    int n4 = (BATCH * HW * CH) / 4;  // 8388608
    apply_att<<<4096, 256, 0, stream>>>((const f4*)x2, (const f4*)attv,
                                        (f4*)d_out, n4);
}

// Round 5
// 84.965 us; speedup vs baseline: 3.9100x; 1.0441x over previous
//
#include <hip/hip_runtime.h>
#include <math.h>

#define BATCH   16
#define CH      512           // sequence length L == channels
#define HW      4096          // 64*64
#define NCHUNK  64
#define ROWS    (HW / NCHUNK) // 64 rows per chunk
#define DSTATE  16
#define SCHUNK  16            // scan chunks per sequence
#define CLEN    (CH / SCHUNK) // 32 steps per chunk
#define APPU    8             // f4 per thread in apply_att

typedef float f4 __attribute__((ext_vector_type(4)));

__device__ __forceinline__ float siluf(float x) {
    return x / (1.0f + expf(-x));
}
__device__ __forceinline__ float softplusf(float x) {
    return (x > 20.0f) ? x : log1pf(expf(x));
}

// ---------------- K1: GAP partial sums, float4 nontemporal ------------------
__global__ void __launch_bounds__(512) gap_partial(const f4* __restrict__ x1,
                                                   f4* __restrict__ partial) {
    int b     = blockIdx.x / NCHUNK;
    int chunk = blockIdx.x % NCHUNK;
    int t  = threadIdx.x;
    int c4 = t & 127;       // float4 column (128 per row of 512 ch)
    int rg = t >> 7;        // 4 row groups
    const f4* p = x1 + ((size_t)b * HW + (size_t)chunk * ROWS) * 128 + c4;
    f4 acc = (f4)(0.f);
    #pragma unroll
    for (int r = rg; r < ROWS; r += 4) {
        f4 v = __builtin_nontemporal_load(p + (size_t)r * 128);
        acc += v;
    }
    __shared__ f4 red[4][128];
    red[rg][c4] = acc;
    __syncthreads();
    if (rg == 0) {
        f4 s = red[0][c4] + red[1][c4] + red[2][c4] + red[3][c4];
        partial[(size_t)(chunk * BATCH + b) * 128 + c4] = s;
    }
}

// ---------------- K2: fused finalize + precompute + parallel scan -----------
// One block per batch, 512 threads. Everything between the two big streaming
// kernels stays in LDS/registers — no global round-trips, one launch.
__global__ void __launch_bounds__(512) mamba_fused(const float* __restrict__ partial,
                                                   const float* __restrict__ in_proj_w,
                                                   const float* __restrict__ conv_w,
                                                   const float* __restrict__ conv_b,
                                                   const float* __restrict__ x_proj_w,
                                                   const float* __restrict__ dt_proj_w,
                                                   const float* __restrict__ dt_proj_b,
                                                   const float* __restrict__ A_log,
                                                   const float* __restrict__ Dp,
                                                   const float* __restrict__ out_proj_w,
                                                   float* __restrict__ att)
{
    int b   = blockIdx.x;
    int tid = threadIdx.x;

    // --- 1) finalize pooled row ---
    __shared__ float pool[CH];
    {
        float s = 0.f;
        #pragma unroll 8
        for (int k = 0; k < NCHUNK; ++k)
            s += partial[(size_t)k * (BATCH * CH) + b * CH + tid];
        pool[tid] = s * (1.0f / (float)HW);
    }
    __syncthreads();

    // --- 2) per-position: conv+silu, gate coef, softplus(dt), skip ---
    __shared__ float sx0[CH], sx1[CH], sdt0[CH], sdt1[CH], scf0[CH], scf1[CH], ssk[CH];
    {
        int l = tid;
        float u0  = pool[l];
        float um1 = (l >= 1) ? pool[l - 1] : 0.f;
        float um2 = (l >= 2) ? pool[l - 2] : 0.f;
        float um3 = (l >= 3) ? pool[l - 3] : 0.f;
        float xs[2], cf[2], dtv[2];
        #pragma unroll
        for (int d = 0; d < 2; ++d) {
            float conv = um3 * conv_w[d * 4 + 0] + um2 * conv_w[d * 4 + 1] +
                         um1 * conv_w[d * 4 + 2] + u0  * conv_w[d * 4 + 3];
            float xc = in_proj_w[d] * conv + conv_b[d];
            xs[d] = siluf(xc);
            float z = u0 * in_proj_w[2 + d];
            cf[d] = siluf(z) * out_proj_w[d];
        }
        float dt_raw = xs[0] * x_proj_w[0] + xs[1] * x_proj_w[1];
        #pragma unroll
        for (int d = 0; d < 2; ++d)
            dtv[d] = softplusf(dt_raw * dt_proj_w[d] + dt_proj_b[d]);
        sx0[l] = xs[0]; sx1[l] = xs[1];
        sdt0[l] = dtv[0]; sdt1[l] = dtv[1];
        scf0[l] = cf[0]; scf1[l] = cf[1];
        ssk[l] = xs[0] * Dp[0] * cf[0] + xs[1] * Dp[1] * cf[1];
    }
    __syncthreads();

    // --- 3) chunked parallel scan: 16 chunks x 32 (d,s) lanes ---
    int ds    = tid & 31;
    int chunk = tid >> 5;
    int si    = ds & 15;
    int d     = ds >> 4;
    float Aval = -expf(A_log[d * DSTATE + si]);
    float wB0 = x_proj_w[(1 + si) * 2],  wB1 = x_proj_w[(1 + si) * 2 + 1];
    float wC0 = x_proj_w[(17 + si) * 2], wC1 = x_proj_w[(17 + si) * 2 + 1];
    const float* sdt = d ? sdt1 : sdt0;
    const float* scf = d ? scf1 : scf0;
    const float* sxd = d ? sx1  : sx0;

    float a_[CLEN], b_[CLEN], c_[CLEN];
    int l0 = chunk * CLEN;
    #pragma unroll
    for (int l = 0; l < CLEN; ++l) {
        int L = l0 + l;
        float x0 = sx0[L], x1v = sx1[L];
        float dt = sdt[L];
        float Bs = x0 * wB0 + x1v * wB1;
        float Cs = x0 * wC0 + x1v * wC1;
        a_[l] = expf(dt * Aval);
        b_[l] = dt * Bs * sxd[L];
        c_[l] = Cs * scf[L];
    }

    // phase 1: per-chunk (P, Q)
    float P = 1.f, Q = 0.f;
    #pragma unroll
    for (int l = 0; l < CLEN; ++l) { P *= a_[l]; Q = fmaf(a_[l], Q, b_[l]); }

    // phase 2: exclusive prefix compose across chunks
    __shared__ float sP[SCHUNK][32], sQ[SCHUNK][32];
    sP[chunk][ds] = P; sQ[chunk][ds] = Q;
    __syncthreads();
    float h = 0.f;
    for (int j = 0; j < chunk; ++j) h = fmaf(sP[j][ds], h, sQ[j][ds]);

    // phase 3: exact in-chunk recurrence + 32-lane reduce
    float* patt = att + (size_t)b * CH + l0;
    #pragma unroll
    for (int l = 0; l < CLEN; ++l) {
        h = fmaf(a_[l], h, b_[l]);
        float p = h * c_[l];
        p += __shfl_xor(p, 1, 32);
        p += __shfl_xor(p, 2, 32);
        p += __shfl_xor(p, 4, 32);
        p += __shfl_xor(p, 8, 32);
        p += __shfl_xor(p, 16, 32);
        if (ds == 0) patt[l] = ssk[l0 + l] + p;
    }
}

// ---------------- K3: out = x2 * att broadcast ------------------------------
// Block = 2048 contiguous f4 (aligned to 128-f4 channel rows; 524288 f4 per
// batch is a multiple of 2048, so batch index and channel sub-index are
// block/thread-constant): ONE att4 load per thread, then 8 independent NT
// loads + 8 NT stores for max memory-level parallelism.
__global__ void __launch_bounds__(256) apply_att(const f4* __restrict__ x2,
                                                 const f4* __restrict__ att4,
                                                 f4* __restrict__ out)
{
    size_t base = (size_t)blockIdx.x * (256 * APPU) + threadIdx.x;
    f4 a = att4[((base >> 19) << 7) + (base & 127)];
    f4 v[APPU];
    #pragma unroll
    for (int k = 0; k < APPU; ++k)
        v[k] = __builtin_nontemporal_load(x2 + base + k * 256);
    #pragma unroll
    for (int k = 0; k < APPU; ++k)
        __builtin_nontemporal_store(v[k] * a, out + base + k * 256);
}

extern "C" void kernel_launch(void* const* d_in, const int* in_sizes, int n_in,
                              void* d_out, int out_size, void* d_ws, size_t ws_size,
                              hipStream_t stream) {
    const float* x1         = (const float*)d_in[0];
    const float* x2         = (const float*)d_in[1];
    const float* in_proj_w  = (const float*)d_in[2];
    const float* conv_w     = (const float*)d_in[3];
    const float* conv_b     = (const float*)d_in[4];
    const float* x_proj_w   = (const float*)d_in[5];
    const float* dt_proj_w  = (const float*)d_in[6];
    const float* dt_proj_b  = (const float*)d_in[7];
    const float* A_log      = (const float*)d_in[8];
    const float* Dp         = (const float*)d_in[9];
    const float* out_proj_w = (const float*)d_in[10];

    float* ws = (float*)d_ws;
    size_t o = 0;
    float* partial = ws + o; o += (size_t)NCHUNK * BATCH * CH;  // 524288
    float* attv    = ws + o; o += BATCH * CH;                   // 8192
    (void)ws_size; (void)in_sizes; (void)n_in; (void)out_size;

    gap_partial<<<BATCH * NCHUNK, 512, 0, stream>>>((const f4*)x1, (f4*)partial);
    mamba_fused<<<BATCH, 512, 0, stream>>>(partial, in_proj_w, conv_w, conv_b,
                                           x_proj_w, dt_proj_w, dt_proj_b,
                                           A_log, Dp, out_proj_w, attv);
    int n4 = (BATCH * HW * CH) / 4;            // 8388608 f4
    int nblk = n4 / (256 * APPU);              // 4096 blocks
    apply_att<<<nblk, 256, 0, stream>>>((const f4*)x2, (const f4*)attv, (f4*)d_out);
}